// Round 1
// baseline (470.804 us; speedup 1.0000x reference)
//
#include <hip/hip_runtime.h>

#define IN_F 128
#define OUT_F 32

// deg[i] = 1.0 (self-loop)
__global__ void k_deg_init(float* __restrict__ deg, int n) {
    int i = blockIdx.x * blockDim.x + threadIdx.x;
    if (i < n) deg[i] = 1.0f;
}

// deg[dst[e]] += 1
__global__ void k_deg_count(const int* __restrict__ dst, float* __restrict__ deg, int E) {
    int e = blockIdx.x * blockDim.x + threadIdx.x;
    if (e < E) atomicAdd(&deg[dst[e]], 1.0f);
}

// dis[i] = rsqrt(deg[i])  (deg >= 1 always due to self-loop)
__global__ void k_dis(const float* __restrict__ deg, float* __restrict__ dis, int n) {
    int i = blockIdx.x * blockDim.x + threadIdx.x;
    if (i < n) dis[i] = rsqrtf(deg[i]);
}

// g[n][f] = (x[n] . W[f]) * dis[n]
// block = 256 threads = 8 nodes x 32 features
__global__ void k_gemm(const float* __restrict__ x, const float* __restrict__ W,
                       const float* __restrict__ dis, float* __restrict__ g, int n) {
    __shared__ float  Wl[IN_F * OUT_F];   // transposed: Wl[k*32 + f]
    __shared__ float4 xl4[8 * 32];        // 8 rows x 128 floats

    int tid = threadIdx.x;

    // stage W transposed (once per block)
    for (int i = tid; i < IN_F * OUT_F; i += 256) {
        int f = i >> 7;        // row of W (OUT_F)
        int k = i & 127;       // col of W (IN_F)
        Wl[k * 32 + f] = W[i];
    }

    int nodeBase = blockIdx.x * 8;
    int row = tid >> 5, c4 = tid & 31;
    int nrow = nodeBase + row;
    if (nrow < n) xl4[row * 32 + c4] = ((const float4*)x)[nrow * 32 + c4];
    __syncthreads();

    int f = tid & 31, nl = tid >> 5;
    int node = nodeBase + nl;
    if (node < n) {
        float acc = 0.f;
        #pragma unroll
        for (int k4 = 0; k4 < 32; ++k4) {
            float4 xv = xl4[nl * 32 + k4];   // broadcast across the 32 f-lanes
            int kb = k4 * 4;
            acc = fmaf(xv.x, Wl[(kb + 0) * 32 + f], acc);
            acc = fmaf(xv.y, Wl[(kb + 1) * 32 + f], acc);
            acc = fmaf(xv.z, Wl[(kb + 2) * 32 + f], acc);
            acc = fmaf(xv.w, Wl[(kb + 3) * 32 + f], acc);
        }
        g[node * OUT_F + f] = acc * dis[node];
    }
}

// out[dst[e]*32+f] += g[src[e]*32+f]   (one thread per edge-feature)
__global__ void k_scatter(const float* __restrict__ g, const int* __restrict__ src,
                          const int* __restrict__ dst, float* __restrict__ out, int E) {
    int t = blockIdx.x * blockDim.x + threadIdx.x;
    int e = t >> 5, f = t & 31;
    if (e < E) {
        int s = src[e];
        int d = dst[e];
        atomicAdd(&out[d * OUT_F + f], g[s * OUT_F + f]);
    }
}

// out[i] = dis[node]*(acc + g[i]) + b[f]   (g[i] term = self-loop message)
__global__ void k_final(const float* __restrict__ g, const float* __restrict__ dis,
                        const float* __restrict__ b, float* __restrict__ out, int n) {
    int i = blockIdx.x * blockDim.x + threadIdx.x;
    if (i < n * OUT_F) {
        int node = i >> 5, f = i & 31;
        out[i] = dis[node] * (out[i] + g[i]) + b[f];
    }
}

extern "C" void kernel_launch(void* const* d_in, const int* in_sizes, int n_in,
                              void* d_out, int out_size, void* d_ws, size_t ws_size,
                              hipStream_t stream) {
    const float* x  = (const float*)d_in[0];
    const int*   ei = (const int*)d_in[1];   // [2, E] int
    const float* W  = (const float*)d_in[2];
    const float* b  = (const float*)d_in[3];
    float* out = (float*)d_out;

    int N = in_sizes[0] / IN_F;   // 100000
    int E = in_sizes[1] / 2;      // 1600000
    const int* src = ei;          // edge_index[0]
    const int* dst = ei + E;      // edge_index[1]

    float* deg = (float*)d_ws;          // N floats
    float* dis = deg + N;               // N floats
    float* g   = dis + N;               // N*32 floats

    hipMemsetAsync(d_out, 0, (size_t)out_size * sizeof(float), stream);

    k_deg_init<<<(N + 255) / 256, 256, 0, stream>>>(deg, N);
    k_deg_count<<<(E + 255) / 256, 256, 0, stream>>>(dst, deg, E);
    k_dis<<<(N + 255) / 256, 256, 0, stream>>>(deg, dis, N);
    k_gemm<<<(N + 7) / 8, 256, 0, stream>>>(x, W, dis, g, N);

    long long tot = (long long)E * OUT_F;
    k_scatter<<<(int)((tot + 255) / 256), 256, 0, stream>>>(g, src, dst, out, E);
    k_final<<<(N * OUT_F + 255) / 256, 256, 0, stream>>>(g, dis, b, out, N);
}